// Round 2
// baseline (709.388 us; speedup 1.0000x reference)
//
#include <hip/hip_runtime.h>
#include <stdint.h>

#define BB 64
#define TT 2048
#define VV 512
#define TOUT 2047   // output rows per batch = T-1
#define NCH 32      // chunks per batch row
#define CH 64       // visits per chunk (NCH*CH = 2048 >= TOUT)

typedef unsigned long long ull;

// Scratch placement (NO d_ws — size unverified, suspected cause of the fault):
//  - chmask (128 KB) + S (2 KB) live in the `times` input (512 KB, unused by math).
//  - wT (1 MB) lives in the head of the `codes` input (256 MB), written AFTER
//    k_maskpass has consumed codes. Harness restores inputs before every launch.

// ---------------- kernel A1: W^T (so column-adds are coalesced row reads) ----
__global__ void k_transpose(const float* __restrict__ W, float* __restrict__ wT) {
  __shared__ float tile[32][33];
  int bx = blockIdx.x, by = blockIdx.y;
  int tx = threadIdx.x, ty = threadIdx.y;   // block (32,8)
#pragma unroll
  for (int i = 0; i < 4; ++i)
    tile[ty + i * 8][tx] = W[(size_t)(by * 32 + ty + i * 8) * VV + bx * 32 + tx];
  __syncthreads();
#pragma unroll
  for (int i = 0; i < 4; ++i)
    wT[(size_t)(bx * 32 + ty + i * 8) * VV + by * 32 + tx] = tile[tx][ty + i * 8];
}

// ---------------- kernel A2: S[u] = bias[u] + sum_v W[u,v] -------------------
__global__ void k_rowsum(const float* __restrict__ W, const float* __restrict__ bias,
                         float* __restrict__ S) {
  int u = blockIdx.x;          // 512 blocks x 64 threads (one wave per row)
  int l = threadIdx.x;
  const float* row = W + (size_t)u * VV;
  float4 a = *(const float4*)(row + 4 * l);
  float4 c = *(const float4*)(row + 256 + 4 * l);
  float s = a.x + a.y + a.z + a.w + c.x + c.y + c.z + c.w;
#pragma unroll
  for (int off = 32; off; off >>= 1) s += __shfl_xor(s, off, 64);
  if (l == 0) S[u] = bias[u] + s;
}

// ---------------- kernel B: codes -> 512-bit visit masks ---------------------
// Mask layout: u64 slot s (0..7): H=s>>2, j=s&3; ballot bit = lane l; v = 256*H + 4*l + j.
// As u32 words w (0..15): H=w>>3, h=w&1, j=(w>>1)&3; bit k -> v = 256H + 128h + 4k + j.
// Visit t's mask is stashed at the first 64 B of each 128-col slice of out row t
// (replicated x4 so each wave in k_scan reads/overwrites only its own slice).
__global__ void k_maskpass(const float* __restrict__ codes, const int* __restrict__ lengths,
                           float* __restrict__ out, ull* __restrict__ chmask) {
  int c = blockIdx.x, b = blockIdx.y;
  int tid = threadIdx.x, lane = tid & 63, w = tid >> 6;
  int validB = min(lengths[b] - 1, TOUT);     // visits t < validB are used
  int t0 = c * CH;
  ull o0 = 0, o1 = 0, o2 = 0, o3 = 0, o4 = 0, o5 = 0, o6 = 0, o7 = 0;
  int tstart = t0 + w * (CH / 4);             // 16 visits per wave
#pragma unroll 1
  for (int i = 0; i < CH / 4; ++i) {
    int t = tstart + i;
    if (t >= validB) break;                   // wave-uniform
    const float* cp = codes + ((size_t)b * TT + t) * VV;
    float4 fa = *(const float4*)(cp + 4 * lane);
    float4 fb = *(const float4*)(cp + 256 + 4 * lane);
    ull b0 = __ballot(fa.x != 0.f);
    ull b1 = __ballot(fa.y != 0.f);
    ull b2 = __ballot(fa.z != 0.f);
    ull b3 = __ballot(fa.w != 0.f);
    ull b4 = __ballot(fb.x != 0.f);
    ull b5 = __ballot(fb.y != 0.f);
    ull b6 = __ballot(fb.z != 0.f);
    ull b7 = __ballot(fb.w != 0.f);
    o0 |= b0; o1 |= b1; o2 |= b2; o3 |= b3;
    o4 |= b4; o5 |= b5; o6 |= b6; o7 |= b7;
    float* rowp = out + (size_t)(b * TOUT + t) * VV;
    if (lane < 32) {
      int s = lane & 7, rep = lane >> 3;
      ull v;
      switch (s) {
        case 0: v = b0; break; case 1: v = b1; break;
        case 2: v = b2; break; case 3: v = b3; break;
        case 4: v = b4; break; case 5: v = b5; break;
        case 6: v = b6; break; default: v = b7; break;
      }
      ((ull*)(rowp + rep * 128))[s] = v;
    }
  }
  __shared__ ull red[4][8];
  if (lane == 0) {
    red[w][0] = o0; red[w][1] = o1; red[w][2] = o2; red[w][3] = o3;
    red[w][4] = o4; red[w][5] = o5; red[w][6] = o6; red[w][7] = o7;
  }
  __syncthreads();
  if (tid < 8) {
    ull m = red[0][tid] | red[1][tid] | red[2][tid] | red[3][tid];
    chmask[((size_t)b * NCH + c) * 8 + tid] = m;
  }
}

__device__ __forceinline__ int decode_v(int w, int k) {
  return ((w >> 3) << 8) | ((w & 1) << 7) | (k << 2) | ((w >> 1) & 3);
}

// ---------------- kernel C: incremental scan + store -------------------------
__global__ void k_scan(const float* __restrict__ wT, const float* __restrict__ S,
                       const float* __restrict__ bias, const int* __restrict__ lengths,
                       float* out, const ull* __restrict__ chmask) {
  int c = blockIdx.x, b = blockIdx.y;
  int tid = threadIdx.x, lane = tid & 63, w = tid >> 6;
  int col = w * 128 + 2 * lane;               // wave w owns cols [128w,128w+128)
  int myw = lane & 15;                        // mask word this lane tracks
  int validB = min(lengths[b] - 1, TOUT);
  int t0 = c * CH, t1 = min(t0 + CH, TOUT);
  int pe = min(t1, validB);                   // phase-1 end

  if (t0 < pe) {
    // --- prefix set at chunk start: OR of preceding chunk masks ---
    uint32_t Pw = 0;
    const uint32_t* cm = (const uint32_t*)chmask;
    for (int cc = 0; cc < c; ++cc)
      Pw |= cm[((size_t)b * NCH + cc) * 16 + myw];
    int pc = __popc(Pw);
    pc += __shfl_xor(pc, 1, 64);
    pc += __shfl_xor(pc, 2, 64);
    pc += __shfl_xor(pc, 4, 64);
    pc += __shfl_xor(pc, 8, 64);              // total popcount of P (words replicated x4)
    bool direct = (pc <= 256);                // sum smaller side: present vs absent
    float2 L = direct ? make_float2(bias[col], bias[col + 1])
                      : make_float2(S[col], S[col + 1]);
#pragma unroll 1
    for (int ww = 0; ww < 16; ++ww) {
      uint32_t bits = (uint32_t)__shfl((int)Pw, ww, 64);
      if (!direct) bits = ~bits;
      while (bits) {
        int k = __ffs(bits) - 1; bits &= bits - 1;
        int v = decode_v(ww, k);
        float2 f = *(const float2*)(wT + (size_t)v * VV + col);
        if (direct) { L.x += f.x; L.y += f.y; } else { L.x -= f.x; L.y -= f.y; }
      }
    }
    // --- visit loop: almost always "no new codes" -> just store ---
    uint32_t vm_next =
        ((const uint32_t*)(out + (size_t)(b * TOUT + t0) * VV + w * 128))[myw];
#pragma unroll 1
    for (int t = t0; t < pe; ++t) {
      uint32_t vm = vm_next;
      if (t + 1 < pe)
        vm_next =
            ((const uint32_t*)(out + (size_t)(b * TOUT + t + 1) * VV + w * 128))[myw];
      uint32_t cand = vm & ~Pw;
      if (__ballot(cand != 0)) {              // rare slow path
#pragma unroll 1
        for (int ww = 0; ww < 16; ++ww) {
          uint32_t nb = (uint32_t)__shfl((int)cand, ww, 64);
          if (!nb) continue;
          if (myw == ww) Pw |= nb;
          uint32_t bits = nb;
          while (bits) {
            int k = __ffs(bits) - 1; bits &= bits - 1;
            int v = decode_v(ww, k);
            float2 f = *(const float2*)(wT + (size_t)v * VV + col);
            L.x += f.x; L.y += f.y;
          }
        }
      }
      *(float2*)(out + (size_t)(b * TOUT + t) * VV + col) = L;
    }
  }
  // --- zero rows t >= len-1 (cooperative float4 stores, whole block) ---
  int z0 = max(t0, validB);
  if (z0 < t1) {
    size_t base = (size_t)(b * TOUT + z0) * VV;
    size_t n = (size_t)(t1 - z0) * VV;
    float4 z = make_float4(0.f, 0.f, 0.f, 0.f);
    for (size_t i = (size_t)tid * 4; i < n; i += 256 * 4)
      *(float4*)(out + base + i) = z;
  }
}

extern "C" void kernel_launch(void* const* d_in, const int* in_sizes, int n_in,
                              void* d_out, int out_size, void* d_ws, size_t ws_size,
                              hipStream_t stream) {
  // inputs: times[B,T] (unused), codes[B,T,V] f32, lengths[B] i32, W[V,V] f32, b[V] f32
  float* times_scratch = (float*)d_in[0];     // 512 KB scratch (times unused by math)
  float* codes = (float*)d_in[1];
  const int* lengths = (const int*)d_in[2];
  const float* W = (const float*)d_in[3];
  const float* bias = (const float*)d_in[4];
  float* out = (float*)d_out;

  // scratch layout: chmask = times[0 .. 128 KB), S = times[128 KB .. +2 KB)
  //                 wT     = codes[0 .. 1 MB)   (written after k_maskpass reads codes)
  ull* chmask = (ull*)times_scratch;
  float* S = times_scratch + (128 * 1024 / 4);
  float* wT = codes;

  k_maskpass<<<dim3(NCH, BB), dim3(256), 0, stream>>>(codes, lengths, out, chmask);
  k_transpose<<<dim3(16, 16), dim3(32, 8), 0, stream>>>(W, wT);
  k_rowsum<<<dim3(512), dim3(64), 0, stream>>>(W, bias, S);
  k_scan<<<dim3(NCH, BB), dim3(256), 0, stream>>>(wT, S, bias, lengths, out, chmask);
}

// Round 3
// 650.514 us; speedup vs baseline: 1.0905x; 1.0905x over previous
//
#include <hip/hip_runtime.h>
#include <stdint.h>

#define BB 64
#define TT 2048
#define VV 512
#define TOUT 2047   // output rows per batch = T-1
#define NCH 32      // chunks per batch row
#define CH 64       // visits per chunk (NCH*CH = 2048 >= TOUT)

typedef unsigned long long ull;

// Scratch: chmask (128 KB) + S (2 KB) in `times` input (512 KB, unused by math).
// wT (1 MB) in head of `codes` (written after k_maskpass has consumed codes).
// Per-visit 512-bit masks stashed in the first 64 B of each 128-col slice of the
// output row (replicated x4: one copy per k_scan wave) — overwritten by k_scan.

// ---------------- kernel A1: W^T (column-adds become coalesced row reads) ----
__global__ void k_transpose(const float* __restrict__ W, float* __restrict__ wT) {
  __shared__ float tile[32][33];
  int bx = blockIdx.x, by = blockIdx.y;
  int tx = threadIdx.x, ty = threadIdx.y;   // block (32,8)
#pragma unroll
  for (int i = 0; i < 4; ++i)
    tile[ty + i * 8][tx] = W[(size_t)(by * 32 + ty + i * 8) * VV + bx * 32 + tx];
  __syncthreads();
#pragma unroll
  for (int i = 0; i < 4; ++i)
    wT[(size_t)(bx * 32 + ty + i * 8) * VV + by * 32 + tx] = tile[tx][ty + i * 8];
}

// ---------------- kernel A2: S[u] = bias[u] + sum_v W[u,v] -------------------
__global__ void k_rowsum(const float* __restrict__ W, const float* __restrict__ bias,
                         float* __restrict__ S) {
  int u = blockIdx.x;          // 512 blocks x 64 threads (one wave per row)
  int l = threadIdx.x;
  const float* row = W + (size_t)u * VV;
  float4 a = *(const float4*)(row + 4 * l);
  float4 c = *(const float4*)(row + 256 + 4 * l);
  float s = a.x + a.y + a.z + a.w + c.x + c.y + c.z + c.w;
#pragma unroll
  for (int off = 32; off; off >>= 1) s += __shfl_xor(s, off, 64);
  if (l == 0) S[u] = bias[u] + s;
}

// ---------------- kernel B: codes -> 512-bit visit masks ---------------------
// u64 slot s: H=s>>2, j=s&3, ballot bit l -> v = 256H + 4l + j.
// u32 word w = half (w&1) of slot (w>>1); bit k -> v = 256(w>>3) + 128(w&1) + 4k + ((w>>1)&3).
__global__ void k_maskpass(const float* __restrict__ codes, const int* __restrict__ lengths,
                           float* __restrict__ out, ull* __restrict__ chmask) {
  int c = blockIdx.x, b = blockIdx.y;
  int tid = threadIdx.x, lane = tid & 63, w = tid >> 6;
  int validB = min(lengths[b] - 1, TOUT);
  int tstart = c * CH + w * 16;             // 16 visits per wave
  int n = min(16, validB - tstart);
  ull o0 = 0, o1 = 0, o2 = 0, o3 = 0, o4 = 0, o5 = 0, o6 = 0, o7 = 0;
  int ww = lane & 15, rep = lane >> 4;      // this lane stores word ww of replica rep
  int s = ww >> 1;
  if (n > 0) {
    const float* cp = codes + ((size_t)b * TT + tstart) * VV;
    uint32_t* sp =
        (uint32_t*)((char*)(out + (size_t)(b * TOUT + tstart) * VV) + rep * 512) + ww;
    float4 fa = *(const float4*)(cp + 4 * lane);
    float4 fb = *(const float4*)(cp + 256 + 4 * lane);
#pragma unroll 1
    for (int i = 0; i < n; ++i) {
      float4 na, nb;
      if (i + 1 < n) {                      // depth-2 prefetch (wave-uniform)
        na = *(const float4*)(cp + VV + 4 * lane);
        nb = *(const float4*)(cp + VV + 256 + 4 * lane);
      }
      ull b0 = __ballot(fa.x != 0.f);
      ull b1 = __ballot(fa.y != 0.f);
      ull b2 = __ballot(fa.z != 0.f);
      ull b3 = __ballot(fa.w != 0.f);
      ull b4 = __ballot(fb.x != 0.f);
      ull b5 = __ballot(fb.y != 0.f);
      ull b6 = __ballot(fb.z != 0.f);
      ull b7 = __ballot(fb.w != 0.f);
      o0 |= b0; o1 |= b1; o2 |= b2; o3 |= b3;
      o4 |= b4; o5 |= b5; o6 |= b6; o7 |= b7;
      // branch-free select of word ww (v_cndmask tree, no divergence)
      ull m01 = (s & 1) ? b1 : b0;
      ull m23 = (s & 1) ? b3 : b2;
      ull m45 = (s & 1) ? b5 : b4;
      ull m67 = (s & 1) ? b7 : b6;
      ull m03 = (s & 2) ? m23 : m01;
      ull m47 = (s & 2) ? m67 : m45;
      ull mm = (s & 4) ? m47 : m03;
      uint32_t val = (ww & 1) ? (uint32_t)(mm >> 32) : (uint32_t)mm;
      *sp = val;                            // 64 lanes -> 4 x 64 B coalesced pieces
      sp += VV;                             // next row (u32 stride = 512)
      cp += VV;
      fa = na; fb = nb;
    }
  }
  __shared__ ull red[4][8];
  if (lane == 0) {
    red[w][0] = o0; red[w][1] = o1; red[w][2] = o2; red[w][3] = o3;
    red[w][4] = o4; red[w][5] = o5; red[w][6] = o6; red[w][7] = o7;
  }
  __syncthreads();
  if (tid < 8) {
    ull m = red[0][tid] | red[1][tid] | red[2][tid] | red[3][tid];
    chmask[((size_t)b * NCH + c) * 8 + tid] = m;
  }
}

__device__ __forceinline__ int decode_v(int w, int k) {
  return ((w >> 3) << 8) | ((w & 1) << 7) | (k << 2) | ((w >> 1) & 3);
}

// ---------------- kernel C: incremental scan + store -------------------------
__global__ void k_scan(const float* __restrict__ wT, const float* __restrict__ S,
                       const float* __restrict__ bias, const int* __restrict__ lengths,
                       float* out, const ull* __restrict__ chmask) {
  int c = blockIdx.x, b = blockIdx.y;
  int tid = threadIdx.x, lane = tid & 63, w = tid >> 6;
  int col = w * 128 + 2 * lane;               // wave w owns cols [128w,128w+128)
  int myw = lane & 15;                        // mask word this lane tracks
  int validB = min(lengths[b] - 1, TOUT);
  int t0 = c * CH, t1 = min(t0 + CH, TOUT);
  int pe = min(t1, validB);                   // phase-1 end

  if (t0 < pe) {
    // --- prefix set at chunk start: OR of preceding chunk masks ---
    uint32_t Pw = 0;
    const uint32_t* cm = (const uint32_t*)chmask;
    for (int cc = 0; cc < c; ++cc)
      Pw |= cm[((size_t)b * NCH + cc) * 16 + myw];
    int pc = __popc(Pw);
    pc += __shfl_xor(pc, 1, 64);
    pc += __shfl_xor(pc, 2, 64);
    pc += __shfl_xor(pc, 4, 64);
    pc += __shfl_xor(pc, 8, 64);              // total popcount (words replicated x4)
    bool direct = (pc <= 256);                // sum the smaller side
    float2 L = direct ? make_float2(bias[col], bias[col + 1])
                      : make_float2(S[col], S[col + 1]);
#pragma unroll 1
    for (int ww = 0; ww < 16; ++ww) {
      uint32_t bits = (uint32_t)__shfl((int)Pw, ww, 64);
      if (!direct) bits = ~bits;
      while (bits) {
        int k = __ffs(bits) - 1; bits &= bits - 1;
        int v = decode_v(ww, k);
        float2 f = *(const float2*)(wT + (size_t)v * VV + col);
        if (direct) { L.x += f.x; L.y += f.y; } else { L.x -= f.x; L.y -= f.y; }
      }
    }
    const uint32_t* stash =
        (const uint32_t*)(out + (size_t)b * TOUT * VV + (size_t)w * 128) + myw;
    float2* op = (float2*)(out + (size_t)b * TOUT * VV) + (col >> 1);
    // --- main loop: half-chunks of 16; phase A = batched mask loads (pipelined),
    //     phase B = register-only processing + fire-and-forget stores ---
    int base = t0;
    for (; base + 16 <= pe; base += 16) {
      uint32_t vmr[16];
#pragma unroll
      for (int i = 0; i < 16; ++i)
        vmr[i] = stash[(size_t)(base + i) * VV];
#pragma unroll
      for (int i = 0; i < 16; ++i) {
        uint32_t cand = vmr[i] & ~Pw;
        if (__ballot(cand != 0)) {            // rare slow path
#pragma unroll 1
          for (int ww = 0; ww < 16; ++ww) {
            uint32_t nb = (uint32_t)__shfl((int)cand, ww, 64);
            if (!nb) continue;
            if (myw == ww) Pw |= nb;
            uint32_t bits = nb;
            while (bits) {
              int k = __ffs(bits) - 1; bits &= bits - 1;
              int v = decode_v(ww, k);
              float2 f = *(const float2*)(wT + (size_t)v * VV + col);
              L.x += f.x; L.y += f.y;
            }
          }
        }
        op[(size_t)(base + i) * 256] = L;
      }
    }
    // --- tail (< 16 visits) ---
#pragma unroll 1
    for (; base < pe; ++base) {
      uint32_t cand = stash[(size_t)base * VV] & ~Pw;
      if (__ballot(cand != 0)) {
#pragma unroll 1
        for (int ww = 0; ww < 16; ++ww) {
          uint32_t nb = (uint32_t)__shfl((int)cand, ww, 64);
          if (!nb) continue;
          if (myw == ww) Pw |= nb;
          uint32_t bits = nb;
          while (bits) {
            int k = __ffs(bits) - 1; bits &= bits - 1;
            int v = decode_v(ww, k);
            float2 f = *(const float2*)(wT + (size_t)v * VV + col);
            L.x += f.x; L.y += f.y;
          }
        }
      }
      op[(size_t)base * 256] = L;
    }
  }
  // --- zero rows t >= len-1 (cooperative float4 stores, whole block) ---
  int z0 = max(t0, validB);
  if (z0 < t1) {
    size_t basep = (size_t)(b * TOUT + z0) * VV;
    size_t n = (size_t)(t1 - z0) * VV;
    float4 z = make_float4(0.f, 0.f, 0.f, 0.f);
    for (size_t i = (size_t)tid * 4; i < n; i += 256 * 4)
      *(float4*)(out + basep + i) = z;
  }
}

extern "C" void kernel_launch(void* const* d_in, const int* in_sizes, int n_in,
                              void* d_out, int out_size, void* d_ws, size_t ws_size,
                              hipStream_t stream) {
  // inputs: times[B,T] (unused), codes[B,T,V] f32, lengths[B] i32, W[V,V] f32, b[V] f32
  float* times_scratch = (float*)d_in[0];     // 512 KB scratch (times unused by math)
  float* codes = (float*)d_in[1];
  const int* lengths = (const int*)d_in[2];
  const float* W = (const float*)d_in[3];
  const float* bias = (const float*)d_in[4];
  float* out = (float*)d_out;

  ull* chmask = (ull*)times_scratch;                 // 128 KB
  float* S = times_scratch + (128 * 1024 / 4);       // 2 KB
  float* wT = codes;                                 // 1 MB, written after maskpass

  k_maskpass<<<dim3(NCH, BB), dim3(256), 0, stream>>>(codes, lengths, out, chmask);
  k_transpose<<<dim3(16, 16), dim3(32, 8), 0, stream>>>(W, wT);
  k_rowsum<<<dim3(512), dim3(64), 0, stream>>>(W, bias, S);
  k_scan<<<dim3(NCH, BB), dim3(256), 0, stream>>>(wT, S, bias, lengths, out, chmask);
}

// Round 4
// 549.681 us; speedup vs baseline: 1.2905x; 1.1834x over previous
//
#include <hip/hip_runtime.h>
#include <stdint.h>

#define BB 64
#define TT 2048
#define VV 512
#define TOUT 2047   // output rows per batch = T-1
#define NCH 32      // chunks per batch row
#define CH 64       // visits per chunk

typedef unsigned long long ull;
typedef float f32x2 __attribute__((ext_vector_type(2)));
typedef float f32x4 __attribute__((ext_vector_type(4)));

// Scratch: chmask (128 KB) + S (2 KB) in `times` input (unused by math).
// wT (1 MB) in head of `codes` (written after k_maskpass consumed codes).
// Per-visit 512-bit masks stashed in first 64 B of each 128-col slice of the
// output row (x4 replicas, one per k_scan wave); k_scan reads them via a
// separate __restrict__ pointer (materially disjoint rows) then overwrites.

// ---------------- kernel A1: W^T ---------------------------------------------
__global__ void k_transpose(const float* __restrict__ W, float* __restrict__ wT) {
  __shared__ float tile[32][33];
  int bx = blockIdx.x, by = blockIdx.y;
  int tx = threadIdx.x, ty = threadIdx.y;   // block (32,8)
#pragma unroll
  for (int i = 0; i < 4; ++i)
    tile[ty + i * 8][tx] = W[(size_t)(by * 32 + ty + i * 8) * VV + bx * 32 + tx];
  __syncthreads();
#pragma unroll
  for (int i = 0; i < 4; ++i)
    wT[(size_t)(bx * 32 + ty + i * 8) * VV + by * 32 + tx] = tile[tx][ty + i * 8];
}

// ---------------- kernel A2: S[u] = bias[u] + sum_v W[u,v] -------------------
__global__ void k_rowsum(const float* __restrict__ W, const float* __restrict__ bias,
                         float* __restrict__ S) {
  int u = blockIdx.x;
  int l = threadIdx.x;
  const float* row = W + (size_t)u * VV;
  float4 a = *(const float4*)(row + 4 * l);
  float4 c = *(const float4*)(row + 256 + 4 * l);
  float s = a.x + a.y + a.z + a.w + c.x + c.y + c.z + c.w;
#pragma unroll
  for (int off = 32; off; off >>= 1) s += __shfl_xor(s, off, 64);
  if (l == 0) S[u] = bias[u] + s;
}

// ---------------- kernel B: codes -> 512-bit visit masks ---------------------
// u32 word w: bit k -> v = 256(w>>3) + 128(w&1) + 4k + ((w>>1)&3)
__global__ void k_maskpass(const float* __restrict__ codes, const int* __restrict__ lengths,
                           uint32_t* __restrict__ stashw, ull* __restrict__ chmask) {
  int b = blockIdx.y;
  int c = (blockIdx.x + b) & 31;            // XCD/CU spread swizzle
  int tid = threadIdx.x, lane = tid & 63, w = tid >> 6;
  int validB = min(lengths[b] - 1, TOUT);
  int tstart = c * CH + w * 16;
  int n = min(16, validB - tstart);         // may be <= 0
  ull o0 = 0, o1 = 0, o2 = 0, o3 = 0, o4 = 0, o5 = 0, o6 = 0, o7 = 0;
  int ww = lane & 15, rep = lane >> 4, s = ww >> 1;
  const float* cp0 = codes + ((size_t)b * TT + tstart) * VV;
  uint32_t* sp0 = stashw + (size_t)(b * TOUT + tstart) * VV + rep * 128 + ww;
#pragma unroll 1
  for (int i0 = 0; i0 < n; i0 += 4) {       // groups of 4 visits, 8 loads in flight
    int m = min(4, n - i0);                 // wave-uniform
    f32x4 fa[4], fb[4];
#pragma unroll
    for (int j = 0; j < 4; ++j)
      if (j < m) {
        const float* cp = cp0 + (size_t)(i0 + j) * VV;
        fa[j] = __builtin_nontemporal_load((const f32x4*)(cp + 4 * lane));
        fb[j] = __builtin_nontemporal_load((const f32x4*)(cp + 256 + 4 * lane));
      }
#pragma unroll
    for (int j = 0; j < 4; ++j)
      if (j < m) {
        ull b0 = __ballot(fa[j][0] != 0.f);
        ull b1 = __ballot(fa[j][1] != 0.f);
        ull b2 = __ballot(fa[j][2] != 0.f);
        ull b3 = __ballot(fa[j][3] != 0.f);
        ull b4 = __ballot(fb[j][0] != 0.f);
        ull b5 = __ballot(fb[j][1] != 0.f);
        ull b6 = __ballot(fb[j][2] != 0.f);
        ull b7 = __ballot(fb[j][3] != 0.f);
        o0 |= b0; o1 |= b1; o2 |= b2; o3 |= b3;
        o4 |= b4; o5 |= b5; o6 |= b6; o7 |= b7;
        ull m01 = (s & 1) ? b1 : b0;
        ull m23 = (s & 1) ? b3 : b2;
        ull m45 = (s & 1) ? b5 : b4;
        ull m67 = (s & 1) ? b7 : b6;
        ull m03 = (s & 2) ? m23 : m01;
        ull m47 = (s & 2) ? m67 : m45;
        ull mm = (s & 4) ? m47 : m03;
        uint32_t val = (ww & 1) ? (uint32_t)(mm >> 32) : (uint32_t)mm;
        sp0[(size_t)(i0 + j) * VV] = val;   // 4 x 64 B segments, one instr
      }
  }
  __shared__ ull red[4][8];
  if (lane == 0) {
    red[w][0] = o0; red[w][1] = o1; red[w][2] = o2; red[w][3] = o3;
    red[w][4] = o4; red[w][5] = o5; red[w][6] = o6; red[w][7] = o7;
  }
  __syncthreads();
  if (tid < 8) {
    ull m = red[0][tid] | red[1][tid] | red[2][tid] | red[3][tid];
    chmask[((size_t)b * NCH + c) * 8 + tid] = m;
  }
}

__device__ __forceinline__ int decode_v(int w, int k) {
  return ((w >> 3) << 8) | ((w & 1) << 7) | (k << 2) | ((w >> 1) & 3);
}

// 4-deep pipelined column adds: bits is wave-uniform; sign = +1/-1
__device__ __forceinline__ void add_bits4(uint32_t bits, int ww, int col,
                                          const float* __restrict__ wT,
                                          float sign, f32x2& L) {
#pragma unroll 1
  while (bits) {
    int k0 = __ffs(bits) - 1; bits &= bits - 1;
    int k1 = -1, k2 = -1, k3 = -1;
    if (bits) { k1 = __ffs(bits) - 1; bits &= bits - 1; }
    if (bits) { k2 = __ffs(bits) - 1; bits &= bits - 1; }
    if (bits) { k3 = __ffs(bits) - 1; bits &= bits - 1; }
    f32x2 f0 = *(const f32x2*)(wT + (size_t)decode_v(ww, k0) * VV + col);
    f32x2 acc = f0;
    if (k1 >= 0) { f32x2 f1 = *(const f32x2*)(wT + (size_t)decode_v(ww, k1) * VV + col);
                   acc += f1; }
    if (k2 >= 0) { f32x2 f2 = *(const f32x2*)(wT + (size_t)decode_v(ww, k2) * VV + col);
                   acc += f2; }
    if (k3 >= 0) { f32x2 f3 = *(const f32x2*)(wT + (size_t)decode_v(ww, k3) * VV + col);
                   acc += f3; }
    L += sign * acc;
  }
}

// ---------------- kernel C: incremental scan + store -------------------------
__global__ void k_scan(const float* __restrict__ wT, const float* __restrict__ S,
                       const float* __restrict__ bias, const int* __restrict__ lengths,
                       float* __restrict__ outw, const uint32_t* __restrict__ stashr,
                       const ull* __restrict__ chmask) {
  int b = blockIdx.y;
  int c = (blockIdx.x + b) & 31;            // XCD/CU spread swizzle
  int tid = threadIdx.x, lane = tid & 63, w = tid >> 6;
  int col = w * 128 + 2 * lane;             // wave w owns cols [128w,128w+128)
  int myw = lane & 15;
  int validB = min(lengths[b] - 1, TOUT);
  int t0 = c * CH, t1 = min(t0 + CH, TOUT);
  int pe = min(t1, validB);

  if (t0 < pe) {
    // --- prefix P at chunk start (unroll-4 OR of chunk masks) ---
    const uint32_t* cm = (const uint32_t*)chmask + (size_t)b * NCH * 16 + myw;
    uint32_t p0 = 0, p1 = 0, p2 = 0, p3 = 0;
    int cc = 0;
    for (; cc + 4 <= c; cc += 4) {
      p0 |= cm[(cc + 0) * 16]; p1 |= cm[(cc + 1) * 16];
      p2 |= cm[(cc + 2) * 16]; p3 |= cm[(cc + 3) * 16];
    }
    for (; cc < c; ++cc) p0 |= cm[cc * 16];
    uint32_t Pw = p0 | p1 | p2 | p3;
    int pc = __popc(Pw);
    pc += __shfl_xor(pc, 1, 64);
    pc += __shfl_xor(pc, 2, 64);
    pc += __shfl_xor(pc, 4, 64);
    pc += __shfl_xor(pc, 8, 64);            // total |P| (x4 replicas)
    bool direct = (pc <= 256);
    f32x2 L;
    if (direct) { L[0] = bias[col]; L[1] = bias[col + 1]; }
    else        { L[0] = S[col];    L[1] = S[col + 1]; }
#pragma unroll 1
    for (int ww = 0; ww < 16; ++ww) {
      uint32_t bits = (uint32_t)__shfl((int)Pw, ww, 64);
      if (!direct) bits = ~bits;
      add_bits4(bits, ww, col, wT, direct ? 1.f : -1.f, L);
    }

    const uint32_t* stash = stashr + (size_t)b * TOUT * VV + w * 128 + myw;
    float* ob = outw + (size_t)b * TOUT * VV + col;
    int nfull = (pe - t0) >> 4;             // full 16-visit batches
    uint32_t vmr[16], vmn[16];
    if (nfull > 0) {
#pragma unroll
      for (int i = 0; i < 16; ++i) vmr[i] = stash[(size_t)(t0 + i) * VV];
    }
#pragma unroll 1
    for (int ib = 0; ib < nfull; ++ib) {
      int base = t0 + ib * 16;
      if (ib + 1 < nfull) {                 // prefetch next batch (restrict: pipelines)
#pragma unroll
        for (int i = 0; i < 16; ++i) vmn[i] = stash[(size_t)(base + 16 + i) * VV];
      }
#pragma unroll
      for (int i = 0; i < 16; ++i) {
        uint32_t cand = vmr[i] & ~Pw;
        uint32_t wwm = (uint32_t)__ballot(cand != 0) & 0xFFFFu;  // words w/ new bits
        while (wwm) {                       // rare slow path, few words
          int ww = __ffs(wwm) - 1; wwm &= wwm - 1;
          uint32_t nb = (uint32_t)__shfl((int)cand, ww, 64);
          if (myw == ww) Pw |= nb;
          add_bits4(nb, ww, col, wT, 1.f, L);
        }
        __builtin_nontemporal_store(L, (f32x2*)(ob + (size_t)(base + i) * VV));
      }
#pragma unroll
      for (int i = 0; i < 16; ++i) vmr[i] = vmn[i];
    }
    // --- tail (< 16 visits) ---
#pragma unroll 1
    for (int t = t0 + nfull * 16; t < pe; ++t) {
      uint32_t cand = stash[(size_t)t * VV] & ~Pw;
      uint32_t wwm = (uint32_t)__ballot(cand != 0) & 0xFFFFu;
      while (wwm) {
        int ww = __ffs(wwm) - 1; wwm &= wwm - 1;
        uint32_t nb = (uint32_t)__shfl((int)cand, ww, 64);
        if (myw == ww) Pw |= nb;
        add_bits4(nb, ww, col, wT, 1.f, L);
      }
      __builtin_nontemporal_store(L, (f32x2*)(ob + (size_t)t * VV));
    }
  }
  // --- zero rows t >= len-1 ---
  int z0 = max(t0, validB);
  if (z0 < t1) {
    size_t basep = (size_t)(b * TOUT + z0) * VV;
    size_t n = (size_t)(t1 - z0) * VV;
    f32x4 z = {0.f, 0.f, 0.f, 0.f};
    for (size_t i = (size_t)tid * 4; i < n; i += 256 * 4)
      __builtin_nontemporal_store(z, (f32x4*)(outw + basep + i));
  }
}

extern "C" void kernel_launch(void* const* d_in, const int* in_sizes, int n_in,
                              void* d_out, int out_size, void* d_ws, size_t ws_size,
                              hipStream_t stream) {
  // inputs: times[B,T] (unused), codes[B,T,V] f32, lengths[B] i32, W[V,V] f32, b[V] f32
  float* times_scratch = (float*)d_in[0];     // 512 KB scratch
  float* codes = (float*)d_in[1];
  const int* lengths = (const int*)d_in[2];
  const float* W = (const float*)d_in[3];
  const float* bias = (const float*)d_in[4];
  float* out = (float*)d_out;

  ull* chmask = (ull*)times_scratch;                 // 128 KB
  float* S = times_scratch + (128 * 1024 / 4);       // 2 KB
  float* wT = codes;                                 // 1 MB, written after maskpass

  k_maskpass<<<dim3(NCH, BB), dim3(256), 0, stream>>>(codes, lengths,
                                                      (uint32_t*)out, chmask);
  k_transpose<<<dim3(16, 16), dim3(32, 8), 0, stream>>>(W, wT);
  k_rowsum<<<dim3(512), dim3(64), 0, stream>>>(W, bias, S);
  k_scan<<<dim3(NCH, BB), dim3(256), 0, stream>>>(wT, S, bias, lengths,
                                                  out, (const uint32_t*)out, chmask);
}